// Round 1
// baseline (1145.774 us; speedup 1.0000x reference)
//
#include <hip/hip_runtime.h>
#include <hip/hip_bf16.h>

// Problem constants (bert-base LayoutLM-ish fusion head)
#define V_PAD  30528   // vocab 30522 rounded up
#define S_LEN  512
#define D_DIM  768
#define J_N    12
#define M_ROWS 1024    // B*S
#define K_MLP  9984    // 13*D
#define N_MLP  9216    // J*D
#define K_ATT  1536    // 2*D
#define N_ATT  768     // D
#define N_LBL  7

using bf16x8 = __attribute__((ext_vector_type(8))) __bf16;
using f32x4  = __attribute__((ext_vector_type(4))) float;

__device__ __forceinline__ unsigned short f2bf(float f) {
  union { float f; unsigned int u; } c; c.f = f;
  unsigned int u = c.u;
  return (unsigned short)((u + 0x7fffu + ((u >> 16) & 1u)) >> 16); // RNE
}

// ---- K2: build last-occurrence tables (dict semantics) ----
__global__ void build_tables_kernel(const int* __restrict__ ids,
                                    int* __restrict__ last0,
                                    int* __restrict__ last01) {
  int p = blockIdx.x * 256 + threadIdx.x;
  if (p < M_ROWS) {
    int id = ids[p];
    atomicMax(&last01[id], p);          // both batches, flat position
    if (p < S_LEN) atomicMax(&last0[id], p); // batch 0 only
  }
}

// ---- K3a: seq -> rij[:, 0:768] (bf16 A-operand for MLP GEMM) ----
__global__ __launch_bounds__(256) void seqrij_kernel(const float* __restrict__ seq,
                                                     unsigned short* __restrict__ rij) {
  int bs = blockIdx.x;
  for (int d = threadIdx.x; d < D_DIM; d += 256)
    rij[(size_t)bs * K_MLP + d] = f2bf(seq[(size_t)bs * D_DIM + d]);
}

// ---- K3b: neighbor gather-sum -> nflat (fp32) and rij[:, 768:] (bf16) ----
__global__ __launch_bounds__(256)
void gather_kernel(const float* __restrict__ seq, const int* __restrict__ nbr,
                   const int* __restrict__ last0, const int* __restrict__ last01,
                   float* __restrict__ nflat, unsigned short* __restrict__ rij) {
  const int bsj = blockIdx.x;          // (b*S + s)*J + j
  const int j  = bsj % J_N;
  const int bs = bsj / J_N;
  const int b  = bs >> 9;              // S=512
  const int* nb = nbr + (size_t)bsj * 4;
  const int* tab = (b == 0) ? last0 : last01;
  const int s0 = tab[nb[0]], s1 = tab[nb[1]], s2 = tab[nb[2]], s3 = tab[nb[3]];
  const int t = threadIdx.x;
#pragma unroll
  for (int u = 0; u < 3; ++u) {        // 768 = 3*256
    int d = t + u * 256;
    float acc = 0.f;
    if (s0 >= 0) acc += seq[(size_t)s0 * D_DIM + d];
    if (s1 >= 0) acc += seq[(size_t)s1 * D_DIM + d];
    if (s2 >= 0) acc += seq[(size_t)s2 * D_DIM + d];
    if (s3 >= 0) acc += seq[(size_t)s3 * D_DIM + d];
    nflat[(size_t)bs * N_MLP + j * D_DIM + d] = acc;
    rij[(size_t)bs * K_MLP + D_DIM + j * D_DIM + d] = f2bf(acc);
  }
}

// ---- K4/K6: NT MFMA GEMM, 128x128 tile, BK=32, m97-style staging.
// A: bf16 [M][K] row-major (lda=K). W: fp32 [N][K] row-major (converted on the fly).
// MODE 0: c = sigmoid(acc + bias) * nflat, written IN-PLACE over nflat.
// MODE 1: out = tanh(acc + bias).
template <int MODE>
__global__ __launch_bounds__(256, 2)
void gemm_nt_kernel(const unsigned short* __restrict__ A,
                    const float* __restrict__ W,
                    const float* __restrict__ bias,
                    float* __restrict__ nflat_c,   // MODE 0 in/out
                    float* __restrict__ outp,      // MODE 1 out
                    int K, int N) {
  __shared__ unsigned short ldsA[128 * 32];   // 8 KB
  __shared__ unsigned short ldsB[128 * 32];   // 8 KB
  const int tid  = threadIdx.x;
  const int lane = tid & 63;
  const int w    = tid >> 6;
  const int m0 = blockIdx.x * 128;
  const int n0 = blockIdx.y * 128;

  f32x4 acc[4][4];
#pragma unroll
  for (int i = 0; i < 4; ++i)
#pragma unroll
    for (int j = 0; j < 4; ++j) acc[i][j] = (f32x4){0.f, 0.f, 0.f, 0.f};

  // A staging: wave w stages rows [w*32, w*32+32), two 1KB global_load_lds ops
  const int ar0 = w * 32 + (lane >> 2);
  const int ac0 = (lane & 3) * 8;
  // B staging: thread covers W row tid>>1, 16 cols at (tid&1)*16
  const int br = tid >> 1;
  const int bc = (tid & 1) * 16;
  const float* gB0 = W + (size_t)(n0 + br) * K + bc;

  const int wm = (w >> 1) * 64, wn = (w & 1) * 64;
  const int fr = lane & 15;
  const int fk = (lane >> 4) * 8;

  for (int kk = 0; kk < K; kk += 32) {
    { // A tile -> LDS (async, bf16 already)
      const unsigned short* g0 = A + (size_t)(m0 + ar0) * K + kk + ac0;
      __builtin_amdgcn_global_load_lds(
          (const __attribute__((address_space(1))) void*)g0,
          (__attribute__((address_space(3))) void*)(&ldsA[(w * 32) * 32]), 16, 0, 0);
      const unsigned short* g1 = g0 + (size_t)16 * K;
      __builtin_amdgcn_global_load_lds(
          (const __attribute__((address_space(1))) void*)g1,
          (__attribute__((address_space(3))) void*)(&ldsA[(w * 32 + 16) * 32]), 16, 0, 0);
    }
    { // W tile fp32 -> bf16 -> LDS
      const float* g = gB0 + kk;
      float4 f0 = *(const float4*)(g + 0);
      float4 f1 = *(const float4*)(g + 4);
      float4 f2 = *(const float4*)(g + 8);
      float4 f3 = *(const float4*)(g + 12);
      union { unsigned short h[16]; uint4 q[2]; } pk;
      pk.h[0]  = f2bf(f0.x); pk.h[1]  = f2bf(f0.y); pk.h[2]  = f2bf(f0.z); pk.h[3]  = f2bf(f0.w);
      pk.h[4]  = f2bf(f1.x); pk.h[5]  = f2bf(f1.y); pk.h[6]  = f2bf(f1.z); pk.h[7]  = f2bf(f1.w);
      pk.h[8]  = f2bf(f2.x); pk.h[9]  = f2bf(f2.y); pk.h[10] = f2bf(f2.z); pk.h[11] = f2bf(f2.w);
      pk.h[12] = f2bf(f3.x); pk.h[13] = f2bf(f3.y); pk.h[14] = f2bf(f3.z); pk.h[15] = f2bf(f3.w);
      uint4* dst = (uint4*)&ldsB[br * 32 + bc];
      dst[0] = pk.q[0];
      dst[1] = pk.q[1];
    }
    __syncthreads();
    bf16x8 aF[4], bF[4];
#pragma unroll
    for (int i = 0; i < 4; ++i) aF[i] = *(const bf16x8*)&ldsA[(wm + i * 16 + fr) * 32 + fk];
#pragma unroll
    for (int j = 0; j < 4; ++j) bF[j] = *(const bf16x8*)&ldsB[(wn + j * 16 + fr) * 32 + fk];
#pragma unroll
    for (int i = 0; i < 4; ++i)
#pragma unroll
      for (int j = 0; j < 4; ++j)
        acc[i][j] = __builtin_amdgcn_mfma_f32_16x16x32_bf16(aF[i], bF[j], acc[i][j], 0, 0, 0);
    __syncthreads();
  }

  // Epilogue. C/D layout: col = lane&15, row = (lane>>4)*4 + reg  [verified m89/m91]
#pragma unroll
  for (int i = 0; i < 4; ++i) {
    int gm0 = m0 + wm + i * 16 + (lane >> 4) * 4;
#pragma unroll
    for (int j = 0; j < 4; ++j) {
      int gn = n0 + wn + j * 16 + (lane & 15);
      float bv = bias[gn];
#pragma unroll
      for (int r = 0; r < 4; ++r) {
        size_t idx = (size_t)(gm0 + r) * N + gn;
        float x = acc[i][j][r] + bv;
        if (MODE == 0) {
          float gg = 1.0f / (1.0f + __expf(-x));
          nflat_c[idx] = gg * nflat_c[idx];
        } else {
          outp[idx] = tanhf(x);
        }
      }
    }
  }
}

// ---- K5: per-token attention: scores, softmax, mix; emit [mix|seq] bf16 ----
__global__ __launch_bounds__(256)
void attn_kernel(const float* __restrict__ seq, const float* __restrict__ c,
                 unsigned short* __restrict__ combined) {
  __shared__ float sc[N_MLP];   // 36 KB: c row
  __shared__ float sq[D_DIM];
  __shared__ float ss[J_N];
  const int m = blockIdx.x;
  const int tid = threadIdx.x, lane = tid & 63, w = tid >> 6;
  const float* crow = c + (size_t)m * N_MLP;
  for (int d = tid; d < N_MLP; d += 256) sc[d] = crow[d];
  for (int d = tid; d < D_DIM; d += 256) sq[d] = seq[(size_t)m * D_DIM + d];
  __syncthreads();
#pragma unroll
  for (int jj = 0; jj < 3; ++jj) {    // 12 scores over 4 waves
    int j = w * 3 + jj;
    float p = 0.f;
    for (int d = lane; d < D_DIM; d += 64) p += sq[d] * sc[j * D_DIM + d];
#pragma unroll
    for (int off = 32; off > 0; off >>= 1) p += __shfl_down(p, off);
    if (lane == 0) ss[j] = p;
  }
  __syncthreads();
  float mx = ss[0];
#pragma unroll
  for (int j = 1; j < J_N; ++j) mx = fmaxf(mx, ss[j]);
  float aw[J_N]; float sum = 0.f;
#pragma unroll
  for (int j = 0; j < J_N; ++j) { aw[j] = __expf(ss[j] - mx); sum += aw[j]; }
  float inv = 1.f / sum;
  for (int d = tid; d < D_DIM; d += 256) {
    float mix = 0.f;
#pragma unroll
    for (int j = 0; j < J_N; ++j) mix += aw[j] * sc[j * D_DIM + d];
    combined[(size_t)m * K_ATT + d]         = f2bf(mix * inv);
    combined[(size_t)m * K_ATT + D_DIM + d] = f2bf(sq[d]);
  }
}

// ---- K7: classifier logits = [seq|attn_out] @ W_cls^T + b_cls ----
__global__ __launch_bounds__(256)
void cls_kernel(const float* __restrict__ seq, const float* __restrict__ attnout,
                const float* __restrict__ Wc, const float* __restrict__ bc,
                float* __restrict__ out) {
  __shared__ float part[N_LBL][256];
  const int m = blockIdx.x, tid = threadIdx.x;
  float p[N_LBL] = {0.f, 0.f, 0.f, 0.f, 0.f, 0.f, 0.f};
  for (int f = tid; f < K_ATT; f += 256) {
    float v = (f < D_DIM) ? seq[(size_t)m * D_DIM + f]
                          : attnout[(size_t)m * D_DIM + (f - D_DIM)];
#pragma unroll
    for (int l = 0; l < N_LBL; ++l) p[l] += v * Wc[l * K_ATT + f];
  }
#pragma unroll
  for (int l = 0; l < N_LBL; ++l) part[l][tid] = p[l];
  __syncthreads();
  for (int s = 128; s > 0; s >>= 1) {
    if (tid < s)
#pragma unroll
      for (int l = 0; l < N_LBL; ++l) part[l][tid] += part[l][tid + s];
    __syncthreads();
  }
  if (tid < N_LBL) out[(size_t)m * N_LBL + tid] = part[tid][0] + bc[tid];
}

extern "C" void kernel_launch(void* const* d_in, const int* in_sizes, int n_in,
                              void* d_out, int out_size, void* d_ws, size_t ws_size,
                              hipStream_t stream) {
  const float* seq   = (const float*)d_in[0];
  const int*   ids   = (const int*)d_in[1];
  const int*   nbr   = (const int*)d_in[2];
  const float* Wmlp  = (const float*)d_in[3];
  const float* bmlp  = (const float*)d_in[4];
  const float* Wattn = (const float*)d_in[5];
  const float* battn = (const float*)d_in[6];
  const float* Wcls  = (const float*)d_in[7];
  const float* bcls  = (const float*)d_in[8];
  float* out = (float*)d_out;

  // Workspace layout (all offsets 16B-aligned); total ~64.7 MB
  char* ws = (char*)d_ws;
  int* last0  = (int*)(ws);
  int* last01 = (int*)(ws + (size_t)V_PAD * 4);
  unsigned short* rij = (unsigned short*)(ws + (size_t)2 * V_PAD * 4);
  float* nflat = (float*)((char*)rij + (size_t)M_ROWS * K_MLP * 2);   // becomes c in-place
  unsigned short* combined = (unsigned short*)((char*)nflat + (size_t)M_ROWS * N_MLP * 4);
  float* attnout = (float*)((char*)combined + (size_t)M_ROWS * K_ATT * 2);

  hipMemsetAsync(last0, 0xFF, (size_t)2 * V_PAD * 4, stream);  // -1 init
  build_tables_kernel<<<(M_ROWS + 255) / 256, 256, 0, stream>>>(ids, last0, last01);
  seqrij_kernel<<<M_ROWS, 256, 0, stream>>>(seq, rij);
  gather_kernel<<<M_ROWS * J_N, 256, 0, stream>>>(seq, nbr, last0, last01, nflat, rij);
  // MLP GEMM: M=1024, N=9216, K=9984; grid.x = m-tiles (fast) so co-resident
  // blocks share the same W rows through L2/L3.
  gemm_nt_kernel<0><<<dim3(M_ROWS / 128, N_MLP / 128), 256, 0, stream>>>(
      rij, Wmlp, bmlp, nflat, nullptr, K_MLP, N_MLP);
  attn_kernel<<<M_ROWS, 256, 0, stream>>>(seq, nflat, combined);
  gemm_nt_kernel<1><<<dim3(M_ROWS / 128, N_ATT / 128), 256, 0, stream>>>(
      combined, Wattn, battn, nullptr, attnout, K_ATT, N_ATT);
  cls_kernel<<<M_ROWS, 256, 0, stream>>>(seq, attnout, Wcls, bcls, out);
}

// Round 2
// 970.176 us; speedup vs baseline: 1.1810x; 1.1810x over previous
//
#include <hip/hip_runtime.h>
#include <hip/hip_bf16.h>

#define V_PAD  30528
#define S_LEN  512
#define D_DIM  768
#define J_N    12
#define M_ROWS 1024
#define K_MLP  9984
#define N_MLP  9216
#define K_ATT  1536
#define N_ATT  768
#define N_LBL  7

using bf16x8 = __attribute__((ext_vector_type(8))) __bf16;
using f32x4  = __attribute__((ext_vector_type(4))) float;

__device__ __forceinline__ unsigned short f2bf(float f) {
  union { float f; unsigned int u; } c; c.f = f;
  unsigned int u = c.u;
  return (unsigned short)((u + 0x7fffu + ((u >> 16) & 1u)) >> 16); // RNE
}

// ---- fp32 -> bf16 bulk convert (8 elems/thread, 16B stores) ----
__global__ __launch_bounds__(256)
void cvt_bf16_kernel(const float* __restrict__ in, unsigned short* __restrict__ out) {
  size_t i = (size_t)blockIdx.x * 256 + threadIdx.x;
  const float4 f0 = ((const float4*)in)[i * 2];
  const float4 f1 = ((const float4*)in)[i * 2 + 1];
  union { unsigned short h[8]; uint4 q; } pk;
  pk.h[0] = f2bf(f0.x); pk.h[1] = f2bf(f0.y); pk.h[2] = f2bf(f0.z); pk.h[3] = f2bf(f0.w);
  pk.h[4] = f2bf(f1.x); pk.h[5] = f2bf(f1.y); pk.h[6] = f2bf(f1.z); pk.h[7] = f2bf(f1.w);
  ((uint4*)out)[i] = pk.q;
}

// ---- K2: last-occurrence tables (dict semantics) ----
__global__ void build_tables_kernel(const int* __restrict__ ids,
                                    int* __restrict__ last0,
                                    int* __restrict__ last01) {
  int p = blockIdx.x * 256 + threadIdx.x;
  if (p < M_ROWS) {
    int id = ids[p];
    atomicMax(&last01[id], p);
    if (p < S_LEN) atomicMax(&last0[id], p);
  }
}

// ---- K3a: seq -> rij[:, 0:768] bf16 ----
__global__ __launch_bounds__(256) void seqrij_kernel(const float* __restrict__ seq,
                                                     unsigned short* __restrict__ rij) {
  int bs = blockIdx.x;
  for (int d = threadIdx.x; d < D_DIM; d += 256)
    rij[(size_t)bs * K_MLP + d] = f2bf(seq[(size_t)bs * D_DIM + d]);
}

// ---- K3b: neighbor gather-sum -> nflat fp32 and rij[:, 768:] bf16 ----
__global__ __launch_bounds__(256)
void gather_kernel(const float* __restrict__ seq, const int* __restrict__ nbr,
                   const int* __restrict__ last0, const int* __restrict__ last01,
                   float* __restrict__ nflat, unsigned short* __restrict__ rij) {
  const int bsj = blockIdx.x;
  const int j  = bsj % J_N;
  const int bs = bsj / J_N;
  const int b  = bs >> 9;
  const int* nb = nbr + (size_t)bsj * 4;
  const int* tab = (b == 0) ? last0 : last01;
  const int s0 = tab[nb[0]], s1 = tab[nb[1]], s2 = tab[nb[2]], s3 = tab[nb[3]];
  const int t = threadIdx.x;
#pragma unroll
  for (int u = 0; u < 3; ++u) {
    int d = t + u * 256;
    float acc = 0.f;
    if (s0 >= 0) acc += seq[(size_t)s0 * D_DIM + d];
    if (s1 >= 0) acc += seq[(size_t)s1 * D_DIM + d];
    if (s2 >= 0) acc += seq[(size_t)s2 * D_DIM + d];
    if (s3 >= 0) acc += seq[(size_t)s3 * D_DIM + d];
    nflat[(size_t)bs * N_MLP + j * D_DIM + d] = acc;
    rij[(size_t)bs * K_MLP + D_DIM + j * D_DIM + d] = f2bf(acc);
  }
}

// ---- NT MFMA GEMM, TMxTN tile, BK=32, async LDS staging for both operands.
// A: bf16 [M][K]. B (W): bf16 [N][K] if BF16B else fp32 converted on the fly.
// MODE 0: nflat_c = sigmoid(acc+bias) * nflat_c (in-place). MODE 1: out = tanh.
template <int MODE, int TM, int TN, bool BF16B>
__global__ __launch_bounds__(256)
void gemm_nt_kernel(const unsigned short* __restrict__ A,
                    const void* __restrict__ Wv,
                    const float* __restrict__ bias,
                    float* __restrict__ nflat_c,
                    float* __restrict__ outp,
                    int K, int N) {
  constexpr int FM = TM / 32;      // frags per wave in m (wave grid 2x2)
  constexpr int FN = TN / 32;
  __shared__ unsigned short ldsA[TM * 32];
  __shared__ unsigned short ldsB[TN * 32];
  const int tid  = threadIdx.x;
  const int lane = tid & 63;
  const int w    = tid >> 6;
  const int m0 = blockIdx.x * TM;
  const int n0 = blockIdx.y * TN;

  f32x4 acc[FM][FN];
#pragma unroll
  for (int i = 0; i < FM; ++i)
#pragma unroll
    for (int j = 0; j < FN; ++j) acc[i][j] = (f32x4){0.f, 0.f, 0.f, 0.f};

  const int lr = lane >> 2;          // staging: lane -> row-in-16, col
  const int lc = (lane & 3) * 8;
  const int wm = (w >> 1) * (TM / 2), wn = (w & 1) * (TN / 2);
  const int fr = lane & 15;
  const int fk = (lane >> 4) * 8;

  for (int kk = 0; kk < K; kk += 32) {
#pragma unroll
    for (int q = 0; q < TM / 64; ++q) {   // A tile -> LDS, 1KB/wave/inst
      const int r = w * (TM / 4) + q * 16;
      const unsigned short* g = A + (size_t)(m0 + r + lr) * K + kk + lc;
      __builtin_amdgcn_global_load_lds(
          (const __attribute__((address_space(1))) void*)g,
          (__attribute__((address_space(3))) void*)(&ldsA[r * 32]), 16, 0, 0);
    }
    if (BF16B) {
#pragma unroll
      for (int q = 0; q < TN / 64; ++q) { // B tile -> LDS (bf16 pre-converted)
        const int r = w * (TN / 4) + q * 16;
        const unsigned short* g = (const unsigned short*)Wv +
                                  (size_t)(n0 + r + lr) * K + kk + lc;
        __builtin_amdgcn_global_load_lds(
            (const __attribute__((address_space(1))) void*)g,
            (__attribute__((address_space(3))) void*)(&ldsB[r * 32]), 16, 0, 0);
      }
    } else {                              // fp32 W -> bf16 -> LDS fallback
      constexpr int EPT = TN / 8;         // elems per thread (8 or 16)
      constexpr int TPR = 32 / EPT;       // threads per row
      const int br = tid / TPR, bc = (tid % TPR) * EPT;
      const float* g = (const float*)Wv + (size_t)(n0 + br) * K + kk + bc;
      union { unsigned short h[EPT]; uint4 q[EPT / 8]; } pk;
#pragma unroll
      for (int e = 0; e < EPT; e += 4) {
        float4 f = *(const float4*)(g + e);
        pk.h[e] = f2bf(f.x); pk.h[e + 1] = f2bf(f.y);
        pk.h[e + 2] = f2bf(f.z); pk.h[e + 3] = f2bf(f.w);
      }
      uint4* dst = (uint4*)&ldsB[br * 32 + bc];
#pragma unroll
      for (int e = 0; e < EPT / 8; ++e) dst[e] = pk.q[e];
    }
    __syncthreads();
    bf16x8 aF[FM], bF[FN];
#pragma unroll
    for (int i = 0; i < FM; ++i) aF[i] = *(const bf16x8*)&ldsA[(wm + i * 16 + fr) * 32 + fk];
#pragma unroll
    for (int j = 0; j < FN; ++j) bF[j] = *(const bf16x8*)&ldsB[(wn + j * 16 + fr) * 32 + fk];
#pragma unroll
    for (int i = 0; i < FM; ++i)
#pragma unroll
      for (int j = 0; j < FN; ++j)
        acc[i][j] = __builtin_amdgcn_mfma_f32_16x16x32_bf16(aF[i], bF[j], acc[i][j], 0, 0, 0);
    __syncthreads();
  }

  // C/D layout: col = lane&15, row = (lane>>4)*4 + reg  [m89/m91]
#pragma unroll
  for (int i = 0; i < FM; ++i) {
    int gm0 = m0 + wm + i * 16 + (lane >> 4) * 4;
#pragma unroll
    for (int j = 0; j < FN; ++j) {
      int gn = n0 + wn + j * 16 + (lane & 15);
      float bv = bias[gn];
#pragma unroll
      for (int r = 0; r < 4; ++r) {
        size_t idx = (size_t)(gm0 + r) * N + gn;
        float x = acc[i][j][r] + bv;
        if (MODE == 0) {
          float gg = 1.0f / (1.0f + __expf(-x));
          nflat_c[idx] = gg * nflat_c[idx];
        } else {
          outp[idx] = tanhf(x);
        }
      }
    }
  }
}

// ---- K5: attention scores/softmax/mix; emit [mix|seq] bf16 ----
__global__ __launch_bounds__(256)
void attn_kernel(const float* __restrict__ seq, const float* __restrict__ c,
                 unsigned short* __restrict__ combined) {
  __shared__ float sc[N_MLP];
  __shared__ float sq[D_DIM];
  __shared__ float ss[J_N];
  const int m = blockIdx.x;
  const int tid = threadIdx.x, lane = tid & 63, w = tid >> 6;
  const float* crow = c + (size_t)m * N_MLP;
  for (int d = tid; d < N_MLP; d += 256) sc[d] = crow[d];
  for (int d = tid; d < D_DIM; d += 256) sq[d] = seq[(size_t)m * D_DIM + d];
  __syncthreads();
#pragma unroll
  for (int jj = 0; jj < 3; ++jj) {
    int j = w * 3 + jj;
    float p = 0.f;
    for (int d = lane; d < D_DIM; d += 64) p += sq[d] * sc[j * D_DIM + d];
#pragma unroll
    for (int off = 32; off > 0; off >>= 1) p += __shfl_down(p, off);
    if (lane == 0) ss[j] = p;
  }
  __syncthreads();
  float mx = ss[0];
#pragma unroll
  for (int j = 1; j < J_N; ++j) mx = fmaxf(mx, ss[j]);
  float aw[J_N]; float sum = 0.f;
#pragma unroll
  for (int j = 0; j < J_N; ++j) { aw[j] = __expf(ss[j] - mx); sum += aw[j]; }
  float inv = 1.f / sum;
  for (int d = tid; d < D_DIM; d += 256) {
    float mix = 0.f;
#pragma unroll
    for (int j = 0; j < J_N; ++j) mix += aw[j] * sc[j * D_DIM + d];
    combined[(size_t)m * K_ATT + d]         = f2bf(mix * inv);
    combined[(size_t)m * K_ATT + D_DIM + d] = f2bf(sq[d]);
  }
}

// ---- K7: classifier ----
__global__ __launch_bounds__(256)
void cls_kernel(const float* __restrict__ seq, const float* __restrict__ attnout,
                const float* __restrict__ Wc, const float* __restrict__ bc,
                float* __restrict__ out) {
  __shared__ float part[N_LBL][256];
  const int m = blockIdx.x, tid = threadIdx.x;
  float p[N_LBL] = {0.f, 0.f, 0.f, 0.f, 0.f, 0.f, 0.f};
  for (int f = tid; f < K_ATT; f += 256) {
    float v = (f < D_DIM) ? seq[(size_t)m * D_DIM + f]
                          : attnout[(size_t)m * D_DIM + (f - D_DIM)];
#pragma unroll
    for (int l = 0; l < N_LBL; ++l) p[l] += v * Wc[l * K_ATT + f];
  }
#pragma unroll
  for (int l = 0; l < N_LBL; ++l) part[l][tid] = p[l];
  __syncthreads();
  for (int s = 128; s > 0; s >>= 1) {
    if (tid < s)
#pragma unroll
      for (int l = 0; l < N_LBL; ++l) part[l][tid] += part[l][tid + s];
    __syncthreads();
  }
  if (tid < N_LBL) out[(size_t)m * N_LBL + tid] = part[tid][0] + bc[tid];
}

extern "C" void kernel_launch(void* const* d_in, const int* in_sizes, int n_in,
                              void* d_out, int out_size, void* d_ws, size_t ws_size,
                              hipStream_t stream) {
  const float* seq   = (const float*)d_in[0];
  const int*   ids   = (const int*)d_in[1];
  const int*   nbr   = (const int*)d_in[2];
  const float* Wmlp  = (const float*)d_in[3];
  const float* bmlp  = (const float*)d_in[4];
  const float* Wattn = (const float*)d_in[5];
  const float* battn = (const float*)d_in[6];
  const float* Wcls  = (const float*)d_in[7];
  const float* bcls  = (const float*)d_in[8];
  float* out = (float*)d_out;

  // Workspace layout (16B-aligned offsets)
  char* ws = (char*)d_ws;
  size_t off = 0;
  int* last0  = (int*)(ws + off); off += (size_t)V_PAD * 4;
  int* last01 = (int*)(ws + off); off += (size_t)V_PAD * 4;
  unsigned short* rij = (unsigned short*)(ws + off); off += (size_t)M_ROWS * K_MLP * 2;
  float* nflat = (float*)(ws + off); off += (size_t)M_ROWS * N_MLP * 4;   // becomes c in-place
  unsigned short* combined = (unsigned short*)(ws + off); off += (size_t)M_ROWS * K_ATT * 2;
  float* attnout = (float*)(ws + off); off += (size_t)M_ROWS * N_ATT * 4;
  unsigned short* Wb_mlp  = (unsigned short*)(ws + off); off += (size_t)N_MLP * K_MLP * 2;
  unsigned short* Wb_attn = (unsigned short*)(ws + off); off += (size_t)N_ATT * K_ATT * 2;
  const bool big_ws = (ws_size >= off);

  hipMemsetAsync(last0, 0xFF, (size_t)2 * V_PAD * 4, stream);
  build_tables_kernel<<<(M_ROWS + 255) / 256, 256, 0, stream>>>(ids, last0, last01);
  seqrij_kernel<<<M_ROWS, 256, 0, stream>>>(seq, rij);
  gather_kernel<<<M_ROWS * J_N, 256, 0, stream>>>(seq, nbr, last0, last01, nflat, rij);

  if (big_ws) {
    // W -> bf16 once: 184 MB result fits the 256 MiB L3, so the 8 m-tile
    // re-reads in the GEMM hit Infinity Cache instead of HBM.
    cvt_bf16_kernel<<<(N_MLP * K_MLP) / (256 * 8), 256, 0, stream>>>(Wmlp, Wb_mlp);
    cvt_bf16_kernel<<<(N_ATT * K_ATT) / (256 * 8), 256, 0, stream>>>(Wattn, Wb_attn);
    // grid.x = m-tile (8): block b -> XCD b%8 = its m-tile; each XCD streams
    // W once, L3 serves the other seven.
    gemm_nt_kernel<0, 128, 64, true><<<dim3(M_ROWS / 128, N_MLP / 64), 256, 0, stream>>>(
        rij, Wb_mlp, bmlp, nflat, nullptr, K_MLP, N_MLP);
    attn_kernel<<<M_ROWS, 256, 0, stream>>>(seq, nflat, combined);
    gemm_nt_kernel<1, 64, 64, true><<<dim3(M_ROWS / 64, N_ATT / 64), 256, 0, stream>>>(
        combined, Wb_attn, battn, nullptr, attnout, K_ATT, N_ATT);
  } else {
    gemm_nt_kernel<0, 128, 64, false><<<dim3(M_ROWS / 128, N_MLP / 64), 256, 0, stream>>>(
        rij, Wmlp, bmlp, nflat, nullptr, K_MLP, N_MLP);
    attn_kernel<<<M_ROWS, 256, 0, stream>>>(seq, nflat, combined);
    gemm_nt_kernel<1, 64, 64, false><<<dim3(M_ROWS / 64, N_ATT / 64), 256, 0, stream>>>(
        combined, Wattn, battn, nullptr, attnout, K_ATT, N_ATT);
  }
  cls_kernel<<<M_ROWS, 256, 0, stream>>>(seq, attnout, Wcls, bcls, out);
}

// Round 3
// 901.094 us; speedup vs baseline: 1.2715x; 1.0767x over previous
//
#include <hip/hip_runtime.h>
#include <hip/hip_bf16.h>

#define V_PAD  30528
#define S_LEN  512
#define D_DIM  768
#define J_N    12
#define M_ROWS 1024
#define K_MLP  9984
#define N_MLP  9216
#define K_ATT  1536
#define N_ATT  768
#define N_LBL  7

using bf16x8 = __attribute__((ext_vector_type(8))) __bf16;
using f32x4  = __attribute__((ext_vector_type(4))) float;

__device__ __forceinline__ unsigned short f2bf(float f) {
  union { float f; unsigned int u; } c; c.f = f;
  unsigned int u = c.u;
  return (unsigned short)((u + 0x7fffu + ((u >> 16) & 1u)) >> 16); // RNE
}
__device__ __forceinline__ float bf2f(unsigned short h) {
  union { unsigned int u; float f; } c; c.u = (unsigned int)h << 16; return c.f;
}

// ---- fp32 -> bf16 bulk convert ----
__global__ __launch_bounds__(256)
void cvt_bf16_kernel(const float* __restrict__ in, unsigned short* __restrict__ out) {
  size_t i = (size_t)blockIdx.x * 256 + threadIdx.x;
  const float4 f0 = ((const float4*)in)[i * 2];
  const float4 f1 = ((const float4*)in)[i * 2 + 1];
  union { unsigned short h[8]; uint4 q; } pk;
  pk.h[0] = f2bf(f0.x); pk.h[1] = f2bf(f0.y); pk.h[2] = f2bf(f0.z); pk.h[3] = f2bf(f0.w);
  pk.h[4] = f2bf(f1.x); pk.h[5] = f2bf(f1.y); pk.h[6] = f2bf(f1.z); pk.h[7] = f2bf(f1.w);
  ((uint4*)out)[i] = pk.q;
}

// ---- last-occurrence tables (dict semantics) ----
__global__ void build_tables_kernel(const int* __restrict__ ids,
                                    int* __restrict__ last0,
                                    int* __restrict__ last01) {
  int p = blockIdx.x * 256 + threadIdx.x;
  if (p < M_ROWS) {
    int id = ids[p];
    atomicMax(&last01[id], p);
    if (p < S_LEN) atomicMax(&last0[id], p);
  }
}

// ---- seq -> rij[:, 0:768] bf16 ----
__global__ __launch_bounds__(256) void seqrij_kernel(const float* __restrict__ seq,
                                                     unsigned short* __restrict__ rij) {
  int bs = blockIdx.x;
  for (int d = threadIdx.x; d < D_DIM; d += 256)
    rij[(size_t)bs * K_MLP + d] = f2bf(seq[(size_t)bs * D_DIM + d]);
}

// ---- neighbor gather-sum -> rij[:, 768:] bf16 (+ nflat fp32 for fallback) ----
template <bool WRITE_NFLAT>
__global__ __launch_bounds__(192)
void gather_kernel(const float* __restrict__ seq, const int* __restrict__ nbr,
                   const int* __restrict__ last0, const int* __restrict__ last01,
                   float* __restrict__ nflat, unsigned short* __restrict__ rij) {
  const int bsj = blockIdx.x;
  const int j  = bsj % J_N;
  const int bs = bsj / J_N;
  const int b  = bs >> 9;
  const int* nb = nbr + (size_t)bsj * 4;
  const int* tab = (b == 0) ? last0 : last01;
  const int s0 = tab[nb[0]], s1 = tab[nb[1]], s2 = tab[nb[2]], s3 = tab[nb[3]];
  const int d4 = threadIdx.x;            // 0..191, covers 768 floats as float4
  float4 a = {0.f, 0.f, 0.f, 0.f};
  if (s0 >= 0) { float4 v = ((const float4*)(seq + (size_t)s0 * D_DIM))[d4]; a.x += v.x; a.y += v.y; a.z += v.z; a.w += v.w; }
  if (s1 >= 0) { float4 v = ((const float4*)(seq + (size_t)s1 * D_DIM))[d4]; a.x += v.x; a.y += v.y; a.z += v.z; a.w += v.w; }
  if (s2 >= 0) { float4 v = ((const float4*)(seq + (size_t)s2 * D_DIM))[d4]; a.x += v.x; a.y += v.y; a.z += v.z; a.w += v.w; }
  if (s3 >= 0) { float4 v = ((const float4*)(seq + (size_t)s3 * D_DIM))[d4]; a.x += v.x; a.y += v.y; a.z += v.z; a.w += v.w; }
  union { unsigned short h[4]; unsigned long long q; } pk;
  pk.h[0] = f2bf(a.x); pk.h[1] = f2bf(a.y); pk.h[2] = f2bf(a.z); pk.h[3] = f2bf(a.w);
  *(unsigned long long*)(rij + (size_t)bs * K_MLP + D_DIM + j * D_DIM + d4 * 4) = pk.q;
  if (WRITE_NFLAT)
    ((float4*)(nflat + (size_t)bs * N_MLP + j * D_DIM))[d4] = a;
}

// ---- NT MFMA GEMM, TMxTN tile, BK=32, async LDS staging.
// MODE 0: in-place sigmoid gate (fallback). MODE 1: tanh(acc+bias) -> outp.
// MODE 2: raw partial -> outp + blockIdx.z*M*N (split-K; bias applied later).
template <int MODE, int TM, int TN, bool BF16B>
__global__ __launch_bounds__(256)
void gemm_nt_kernel(const unsigned short* __restrict__ A,
                    const void* __restrict__ Wv,
                    const float* __restrict__ bias,
                    float* __restrict__ nflat_c,
                    float* __restrict__ outp,
                    int K, int N, int kchunk) {
  constexpr int FM = TM / 32;
  constexpr int FN = TN / 32;
  __shared__ unsigned short ldsA[TM * 32];
  __shared__ unsigned short ldsB[TN * 32];
  const int tid  = threadIdx.x;
  const int lane = tid & 63;
  const int w    = tid >> 6;
  const int m0 = blockIdx.x * TM;
  const int n0 = blockIdx.y * TN;
  const int kb = blockIdx.z * kchunk;

  f32x4 acc[FM][FN];
#pragma unroll
  for (int i = 0; i < FM; ++i)
#pragma unroll
    for (int j = 0; j < FN; ++j) acc[i][j] = (f32x4){0.f, 0.f, 0.f, 0.f};

  const int lr = lane >> 2;
  const int lc = (lane & 3) * 8;
  const int wm = (w >> 1) * (TM / 2), wn = (w & 1) * (TN / 2);
  const int fr = lane & 15;
  const int fk = (lane >> 4) * 8;

  for (int kk = kb; kk < kb + kchunk; kk += 32) {
#pragma unroll
    for (int q = 0; q < TM / 64; ++q) {   // A tile -> LDS
      const int r = w * (TM / 4) + q * 16;
      const unsigned short* g = A + (size_t)(m0 + r + lr) * K + kk + lc;
      __builtin_amdgcn_global_load_lds(
          (const __attribute__((address_space(1))) void*)g,
          (__attribute__((address_space(3))) void*)(&ldsA[r * 32]), 16, 0, 0);
    }
    if (BF16B) {
#pragma unroll
      for (int q = 0; q < TN / 64; ++q) { // B tile -> LDS (bf16)
        const int r = w * (TN / 4) + q * 16;
        const unsigned short* g = (const unsigned short*)Wv +
                                  (size_t)(n0 + r + lr) * K + kk + lc;
        __builtin_amdgcn_global_load_lds(
            (const __attribute__((address_space(1))) void*)g,
            (__attribute__((address_space(3))) void*)(&ldsB[r * 32]), 16, 0, 0);
      }
    } else {                              // fp32 W -> bf16 -> LDS
      constexpr int EPT = TN / 8;
      constexpr int TPR = 32 / EPT;
      const int br = tid / TPR, bc = (tid % TPR) * EPT;
      const float* g = (const float*)Wv + (size_t)(n0 + br) * K + kk + bc;
      union { unsigned short h[EPT]; uint4 q[EPT / 8]; } pk;
#pragma unroll
      for (int e = 0; e < EPT; e += 4) {
        float4 f = *(const float4*)(g + e);
        pk.h[e] = f2bf(f.x); pk.h[e + 1] = f2bf(f.y);
        pk.h[e + 2] = f2bf(f.z); pk.h[e + 3] = f2bf(f.w);
      }
      uint4* dst = (uint4*)&ldsB[br * 32 + bc];
#pragma unroll
      for (int e = 0; e < EPT / 8; ++e) dst[e] = pk.q[e];
    }
    __syncthreads();
    bf16x8 aF[FM], bF[FN];
#pragma unroll
    for (int i = 0; i < FM; ++i) aF[i] = *(const bf16x8*)&ldsA[(wm + i * 16 + fr) * 32 + fk];
#pragma unroll
    for (int j = 0; j < FN; ++j) bF[j] = *(const bf16x8*)&ldsB[(wn + j * 16 + fr) * 32 + fk];
#pragma unroll
    for (int i = 0; i < FM; ++i)
#pragma unroll
      for (int j = 0; j < FN; ++j)
        acc[i][j] = __builtin_amdgcn_mfma_f32_16x16x32_bf16(aF[i], bF[j], acc[i][j], 0, 0, 0);
    __syncthreads();
  }

  const size_t zoff = (MODE == 2) ? (size_t)blockIdx.z * M_ROWS * N : 0;
  // C/D layout: col = lane&15, row = (lane>>4)*4 + reg  [m89/m91]
#pragma unroll
  for (int i = 0; i < FM; ++i) {
    int gm0 = m0 + wm + i * 16 + (lane >> 4) * 4;
#pragma unroll
    for (int j = 0; j < FN; ++j) {
      int gn = n0 + wn + j * 16 + (lane & 15);
      float bv = (MODE == 2) ? 0.f : bias[gn];
#pragma unroll
      for (int r = 0; r < 4; ++r) {
        size_t idx = (size_t)(gm0 + r) * N + gn;
        float x = acc[i][j][r] + bv;
        if (MODE == 0) {
          float gg = 1.0f / (1.0f + __expf(-x));
          nflat_c[idx] = gg * nflat_c[idx];
        } else if (MODE == 1) {
          outp[idx] = tanhf(x);
        } else {
          outp[zoff + idx] = x;
        }
      }
    }
  }
}

// ---- attention (big path): combine split-K partials + bias + sigmoid gate,
// then scores/softmax/mix; emit [mix|seq] bf16 ----
__global__ __launch_bounds__(256)
void attn_fused_kernel(const float* __restrict__ seq,
                       const float* __restrict__ p0, const float* __restrict__ p1,
                       const float* __restrict__ bmlp,
                       const unsigned short* __restrict__ rij,
                       unsigned short* __restrict__ combined) {
  __shared__ float sc[N_MLP];
  __shared__ float sq[D_DIM];
  __shared__ float ss[J_N];
  const int m = blockIdx.x;
  const int tid = threadIdx.x, lane = tid & 63, w = tid >> 6;
  for (int d = tid; d < D_DIM; d += 256) sq[d] = seq[(size_t)m * D_DIM + d];
  const float* q0 = p0 + (size_t)m * N_MLP;
  const float* q1 = p1 + (size_t)m * N_MLP;
  const unsigned short* nrow = rij + (size_t)m * K_MLP + D_DIM;
  for (int d = tid; d < N_MLP; d += 256) {
    float z = q0[d] + q1[d] + bmlp[d];
    float g = 1.0f / (1.0f + __expf(-z));
    sc[d] = g * bf2f(nrow[d]);
  }
  __syncthreads();
#pragma unroll
  for (int jj = 0; jj < 3; ++jj) {
    int j = w * 3 + jj;
    float p = 0.f;
    for (int d = lane; d < D_DIM; d += 64) p += sq[d] * sc[j * D_DIM + d];
#pragma unroll
    for (int off = 32; off > 0; off >>= 1) p += __shfl_down(p, off);
    if (lane == 0) ss[j] = p;
  }
  __syncthreads();
  float mx = ss[0];
#pragma unroll
  for (int j = 1; j < J_N; ++j) mx = fmaxf(mx, ss[j]);
  float aw[J_N]; float sum = 0.f;
#pragma unroll
  for (int j = 0; j < J_N; ++j) { aw[j] = __expf(ss[j] - mx); sum += aw[j]; }
  float inv = 1.f / sum;
  for (int d = tid; d < D_DIM; d += 256) {
    float mix = 0.f;
#pragma unroll
    for (int j = 0; j < J_N; ++j) mix += aw[j] * sc[j * D_DIM + d];
    combined[(size_t)m * K_ATT + d]         = f2bf(mix * inv);
    combined[(size_t)m * K_ATT + D_DIM + d] = f2bf(sq[d]);
  }
}

// ---- attention (fallback path): c precomputed in nflat_c ----
__global__ __launch_bounds__(256)
void attn_kernel(const float* __restrict__ seq, const float* __restrict__ c,
                 unsigned short* __restrict__ combined) {
  __shared__ float sc[N_MLP];
  __shared__ float sq[D_DIM];
  __shared__ float ss[J_N];
  const int m = blockIdx.x;
  const int tid = threadIdx.x, lane = tid & 63, w = tid >> 6;
  const float* crow = c + (size_t)m * N_MLP;
  for (int d = tid; d < N_MLP; d += 256) sc[d] = crow[d];
  for (int d = tid; d < D_DIM; d += 256) sq[d] = seq[(size_t)m * D_DIM + d];
  __syncthreads();
#pragma unroll
  for (int jj = 0; jj < 3; ++jj) {
    int j = w * 3 + jj;
    float p = 0.f;
    for (int d = lane; d < D_DIM; d += 64) p += sq[d] * sc[j * D_DIM + d];
#pragma unroll
    for (int off = 32; off > 0; off >>= 1) p += __shfl_down(p, off);
    if (lane == 0) ss[j] = p;
  }
  __syncthreads();
  float mx = ss[0];
#pragma unroll
  for (int j = 1; j < J_N; ++j) mx = fmaxf(mx, ss[j]);
  float aw[J_N]; float sum = 0.f;
#pragma unroll
  for (int j = 0; j < J_N; ++j) { aw[j] = __expf(ss[j] - mx); sum += aw[j]; }
  float inv = 1.f / sum;
  for (int d = tid; d < D_DIM; d += 256) {
    float mix = 0.f;
#pragma unroll
    for (int j = 0; j < J_N; ++j) mix += aw[j] * sc[j * D_DIM + d];
    combined[(size_t)m * K_ATT + d]         = f2bf(mix * inv);
    combined[(size_t)m * K_ATT + D_DIM + d] = f2bf(sq[d]);
  }
}

// ---- classifier (shuffle-reduce) ----
__global__ __launch_bounds__(256)
void cls_kernel(const float* __restrict__ seq, const float* __restrict__ attnout,
                const float* __restrict__ Wc, const float* __restrict__ bc,
                float* __restrict__ out) {
  __shared__ float part[4][N_LBL];
  const int m = blockIdx.x, tid = threadIdx.x, lane = tid & 63, w = tid >> 6;
  float p[N_LBL] = {0.f, 0.f, 0.f, 0.f, 0.f, 0.f, 0.f};
  for (int f = tid; f < K_ATT; f += 256) {
    float v = (f < D_DIM) ? seq[(size_t)m * D_DIM + f]
                          : attnout[(size_t)m * D_DIM + (f - D_DIM)];
#pragma unroll
    for (int l = 0; l < N_LBL; ++l) p[l] += v * Wc[l * K_ATT + f];
  }
#pragma unroll
  for (int l = 0; l < N_LBL; ++l) {
#pragma unroll
    for (int off = 32; off > 0; off >>= 1) p[l] += __shfl_down(p[l], off);
  }
  if (lane == 0) {
#pragma unroll
    for (int l = 0; l < N_LBL; ++l) part[w][l] = p[l];
  }
  __syncthreads();
  if (tid < N_LBL)
    out[(size_t)m * N_LBL + tid] =
        part[0][tid] + part[1][tid] + part[2][tid] + part[3][tid] + bc[tid];
}

extern "C" void kernel_launch(void* const* d_in, const int* in_sizes, int n_in,
                              void* d_out, int out_size, void* d_ws, size_t ws_size,
                              hipStream_t stream) {
  const float* seq   = (const float*)d_in[0];
  const int*   ids   = (const int*)d_in[1];
  const int*   nbr   = (const int*)d_in[2];
  const float* Wmlp  = (const float*)d_in[3];
  const float* bmlp  = (const float*)d_in[4];
  const float* Wattn = (const float*)d_in[5];
  const float* battn = (const float*)d_in[6];
  const float* Wcls  = (const float*)d_in[7];
  const float* bcls  = (const float*)d_in[8];
  float* out = (float*)d_out;

  // Common workspace prefix
  char* ws = (char*)d_ws;
  size_t off = 0;
  int* last0  = (int*)(ws + off); off += (size_t)V_PAD * 4;
  int* last01 = (int*)(ws + off); off += (size_t)V_PAD * 4;
  unsigned short* rij = (unsigned short*)(ws + off); off += (size_t)M_ROWS * K_MLP * 2;
  unsigned short* combined = (unsigned short*)(ws + off); off += (size_t)M_ROWS * K_ATT * 2;
  float* attnout = (float*)(ws + off); off += (size_t)M_ROWS * N_ATT * 4;
  const size_t common = off;

  // big: split-K=2 partials, no nflat
  size_t ob = common;
  unsigned short* Wb_mlp  = (unsigned short*)(ws + ob); ob += (size_t)N_MLP * K_MLP * 2;
  unsigned short* Wb_attn = (unsigned short*)(ws + ob); ob += (size_t)N_ATT * K_ATT * 2;
  float* p0 = (float*)(ws + ob); ob += (size_t)M_ROWS * N_MLP * 4;
  float* p1 = (float*)(ws + ob); ob += (size_t)M_ROWS * N_MLP * 4;
  // mid (round-2 proven): nflat + bf16 weights
  size_t om = common;
  float* nflat_m = (float*)(ws + om); om += (size_t)M_ROWS * N_MLP * 4;
  unsigned short* Wm_mlp  = (unsigned short*)(ws + om); om += (size_t)N_MLP * K_MLP * 2;
  unsigned short* Wm_attn = (unsigned short*)(ws + om); om += (size_t)N_ATT * K_ATT * 2;
  // small: nflat only, fp32 W on the fly
  size_t os = common + (size_t)M_ROWS * N_MLP * 4;

  hipMemsetAsync(last0, 0xFF, (size_t)2 * V_PAD * 4, stream);
  build_tables_kernel<<<(M_ROWS + 255) / 256, 256, 0, stream>>>(ids, last0, last01);
  seqrij_kernel<<<M_ROWS, 256, 0, stream>>>(seq, rij);

  if (ws_size >= ob) {
    gather_kernel<false><<<M_ROWS * J_N, 192, 0, stream>>>(seq, nbr, last0, last01, nullptr, rij);
    cvt_bf16_kernel<<<(N_MLP * K_MLP) / (256 * 8), 256, 0, stream>>>(Wmlp, Wb_mlp);
    cvt_bf16_kernel<<<(N_ATT * K_ATT) / (256 * 8), 256, 0, stream>>>(Wattn, Wb_attn);
    // MLP GEMM: 128x128 tile, split-K=2 -> raw partials. grid.x = m-tile so
    // consecutive blocks land on different XCDs but share the same W rows.
    gemm_nt_kernel<2, 128, 128, true><<<dim3(M_ROWS / 128, N_MLP / 128, 2), 256, 0, stream>>>(
        rij, Wb_mlp, nullptr, nullptr, p0, K_MLP, N_MLP, K_MLP / 2);
    attn_fused_kernel<<<M_ROWS, 256, 0, stream>>>(seq, p0, p1, bmlp, rij, combined);
    gemm_nt_kernel<1, 64, 64, true><<<dim3(M_ROWS / 64, N_ATT / 64), 256, 0, stream>>>(
        combined, Wb_attn, battn, nullptr, attnout, K_ATT, N_ATT, K_ATT);
  } else if (ws_size >= om) {
    gather_kernel<true><<<M_ROWS * J_N, 192, 0, stream>>>(seq, nbr, last0, last01, nflat_m, rij);
    cvt_bf16_kernel<<<(N_MLP * K_MLP) / (256 * 8), 256, 0, stream>>>(Wmlp, Wm_mlp);
    cvt_bf16_kernel<<<(N_ATT * K_ATT) / (256 * 8), 256, 0, stream>>>(Wattn, Wm_attn);
    gemm_nt_kernel<0, 128, 64, true><<<dim3(M_ROWS / 128, N_MLP / 64), 256, 0, stream>>>(
        rij, Wm_mlp, bmlp, nflat_m, nullptr, K_MLP, N_MLP, K_MLP);
    attn_kernel<<<M_ROWS, 256, 0, stream>>>(seq, nflat_m, combined);
    gemm_nt_kernel<1, 64, 64, true><<<dim3(M_ROWS / 64, N_ATT / 64), 256, 0, stream>>>(
        combined, Wm_attn, battn, nullptr, attnout, K_ATT, N_ATT, K_ATT);
  } else {
    float* nflat_s = nflat_m;  // same offset, no bf16 weights after it
    (void)os;
    gather_kernel<true><<<M_ROWS * J_N, 192, 0, stream>>>(seq, nbr, last0, last01, nflat_s, rij);
    gemm_nt_kernel<0, 128, 64, false><<<dim3(M_ROWS / 128, N_MLP / 64), 256, 0, stream>>>(
        rij, Wmlp, bmlp, nflat_s, nullptr, K_MLP, N_MLP, K_MLP);
    attn_kernel<<<M_ROWS, 256, 0, stream>>>(seq, nflat_s, combined);
    gemm_nt_kernel<1, 64, 64, false><<<dim3(M_ROWS / 64, N_ATT / 64), 256, 0, stream>>>(
        combined, Wattn, battn, nullptr, attnout, K_ATT, N_ATT, K_ATT);
  }
  cls_kernel<<<M_ROWS, 256, 0, stream>>>(seq, attnout, Wcls, bcls, out);
}